// Round 18
// baseline (47.357 us; speedup 1.0000x reference)
//
#include <hip/hip_runtime.h>
#include <hip/hip_fp16.h>

typedef __attribute__((ext_vector_type(8)))  short short8;
typedef __attribute__((ext_vector_type(8)))  _Float16 half8;
typedef __attribute__((ext_vector_type(16))) float f32x16;
typedef __attribute__((ext_vector_type(2)))  float f32x2;
typedef __attribute__((ext_vector_type(4)))  unsigned int u32x4;

#define NROWS   262144
#define ODIM    64
#define NBLOCKS 256
#define TPB     1024          // 16 waves; 96 KB LDS -> 1 block/CU -> 4 waves/SIMD
#define INV2PI  0.15915494309189535f

__device__ __forceinline__ float cos2pi(float f){ float r; asm("v_cos_f32 %0, %1" : "=v"(r) : "v"(f)); return r; }
__device__ __forceinline__ float sin2pi(float f){ float r; asm("v_sin_f32 %0, %1" : "=v"(r) : "v"(f)); return r; }

__device__ __forceinline__ short f16_of(float f){
    union { _Float16 h; short s; } u; u.h = (_Float16)f; return u.s; }
__device__ __forceinline__ unsigned h2b(__half2 h){
    union { __half2 h; unsigned u; } x; x.h = h; return x.u; }
__device__ __forceinline__ half8 u4h(u32x4 v){ union{u32x4 u; half8 h;} x; x.u = v; return x.h; }
__device__ __forceinline__ half8 s8h(short8 v){ union{short8 s; half8 h;} x; x.s = v; return x.h; }

// one packed rotation: (C,S) <- (C*rc - S*rs, S*rc + C*rs), 2 features/inst
#define ADV(C, S, RC, RS, RN) do {                       \
    const __half2 _cn = __hfma2(C, RC, __hmul2(S, RN));  \
    const __half2 _sn = __hfma2(S, RC, __hmul2(C, RS));  \
    C = _cn; S = _sn;                                    \
} while (0)

// out[b,o] = sum_k F[b,k] W[o,k]; k = br*384 + i*128 + g; harmonic = g+1.
// 32x32x16 f16 MFMA. Pair p (0..23): k-block [p*16, p*16+16), cos + sin branches.
// A lane: row = l&31, k = (l>>5)*8 + j   (self-consistent with B pack below)
// B lane: col = l&31, k = (l>>5)*8 + j
// D:      col = l&31, row = (q&3) + 8*(q>>2) + 4*(l>>5)   [m74/m101, R4/R15-passed]
// Chain per row-tile: half2 = consecutive harmonics (h, h+1); dwords advance
// +2,+2,+2 within a pair, +10 to the next pair; re-anchored every 8 pairs (i-block).
extern "C" __global__ void __launch_bounds__(TPB, 4)
__attribute__((amdgpu_waves_per_eu(4, 4)))
fourier_mfma(const float* __restrict__ x,
             const float* __restrict__ coeffs,
             const float* __restrict__ bias,
             float* __restrict__ out)
{
    // [pair][br][ct][lane] -> short8 f16 (one ds_read_b128 per b-frag)
    __shared__ short8 Wlds[24 * 2 * 2 * 64];   // 98304 B

    const int tid = threadIdx.x;

    // ---- one-time weight staging: fp32 global -> f16 32x32-frags in LDS ----
    for (int fl = tid; fl < 24*2*2*64; fl += TPB) {
        const int ln = fl & 63;
        const int ct = (fl >> 6) & 1;
        const int br = (fl >> 7) & 1;
        const int p  = fl >> 8;
        const int o  = ct*32 + (ln & 31);
        const int kb = p*16 + (ln >> 5)*8;      // 8-run stays inside one i-block
        const int ii = kb >> 7;
        const int g0 = kb & 127;
        const float* wp = coeffs + (((br*ODIM + o)*3 + ii) << 7) + g0;
        union { short8 v; short s[8]; } fr;
        #pragma unroll
        for (int j = 0; j < 8; ++j) fr.s[j] = f16_of(wp[j]);
        Wlds[fl] = fr.v;
    }
    __syncthreads();

    const int lane = tid & 63;
    const int wid  = tid >> 6;
    const int col  = lane & 31;      // A row-in-tile / B col / D col
    const int kbd  = lane >> 5;      // k sub-band (8-wide)
    const float h0 = (float)(kbd*8 + 1);   // lane's anchor harmonic per i-block

    const int unit = blockIdx.x * 16 + wid;   // 4096 units = NROWS/64, exact
    const int base = unit * 64;
    const int rowA = base + col;              // row-tile 0
    const int rowB = base + 32 + col;         // row-tile 1

    f32x2 xr[3];
    #pragma unroll
    for (int i = 0; i < 3; ++i)
        xr[i] = (f32x2){ x[rowA*3 + i] * INV2PI, x[rowB*3 + i] * INV2PI };

    const float bias0 = bias[col];
    const float bias1 = bias[32 + col];

    f32x16 acc[2][2];   // [rt][ct]
    #pragma unroll
    for (int rt = 0; rt < 2; ++rt)
        #pragma unroll
        for (int ct = 0; ct < 2; ++ct)
            #pragma unroll
            for (int q = 0; q < 16; ++q) acc[rt][ct][q] = 0.f;

    // chain state + rotation consts per row-tile (half2 = harmonic pair)
    __half2 C0, S0, C1, S1;
    __half2 c2h0, s2h0, n2h0, c10h0, s10h0, n10h0;
    __half2 c2h1, s2h1, n2h1, c10h1, s10h1, n10h1;

    #pragma unroll 1
    for (int p = 0; p < 24; ++p) {
        // cos b-frags early (chain math below hides LDS latency)
        const short8 bc0 = Wlds[((p*2 + 0)*2 + 0)*64 + lane];
        const short8 bc1 = Wlds[((p*2 + 0)*2 + 1)*64 + lane];

        if ((p & 7) == 0) {                  // re-anchor per i-block (uniform branch)
            const int i = p >> 3;
            const f32x2 a = xr[i];
            {   // row-tile 0
                const float av = a.x;
                float u0 = h0*av;        u0 -= floorf(u0);
                float u1 = (h0+1.f)*av;  u1 -= floorf(u1);
                C0 = __floats2half2_rn(cos2pi(u0), cos2pi(u1));
                S0 = __floats2half2_rn(sin2pi(u0), sin2pi(u1));
                float t2 = 2.f*av;   t2 -= floorf(t2);
                float t10 = 10.f*av; t10 -= floorf(t10);
                const float c2 = cos2pi(t2),  s2 = sin2pi(t2);
                const float c10 = cos2pi(t10), s10 = sin2pi(t10);
                c2h0  = __float2half2_rn(c2);   s2h0  = __float2half2_rn(s2);
                n2h0  = __float2half2_rn(-s2);
                c10h0 = __float2half2_rn(c10);  s10h0 = __float2half2_rn(s10);
                n10h0 = __float2half2_rn(-s10);
            }
            {   // row-tile 1
                const float av = a.y;
                float u0 = h0*av;        u0 -= floorf(u0);
                float u1 = (h0+1.f)*av;  u1 -= floorf(u1);
                C1 = __floats2half2_rn(cos2pi(u0), cos2pi(u1));
                S1 = __floats2half2_rn(sin2pi(u0), sin2pi(u1));
                float t2 = 2.f*av;   t2 -= floorf(t2);
                float t10 = 10.f*av; t10 -= floorf(t10);
                const float c2 = cos2pi(t2),  s2 = sin2pi(t2);
                const float c10 = cos2pi(t10), s10 = sin2pi(t10);
                c2h1  = __float2half2_rn(c2);   s2h1  = __float2half2_rn(s2);
                n2h1  = __float2half2_rn(-s2);
                c10h1 = __float2half2_rn(c10);  s10h1 = __float2half2_rn(s10);
                n10h1 = __float2half2_rn(-s10);
            }
        }

        // fragment dwords straight from chain state (no conversions)
        u32x4 FC0, FC1, FS0, FS1;
        FC0.x = h2b(C0); FS0.x = h2b(S0); FC1.x = h2b(C1); FS1.x = h2b(S1);
        ADV(C0, S0, c2h0,  s2h0,  n2h0);   ADV(C1, S1, c2h1,  s2h1,  n2h1);
        FC0.y = h2b(C0); FS0.y = h2b(S0); FC1.y = h2b(C1); FS1.y = h2b(S1);
        ADV(C0, S0, c2h0,  s2h0,  n2h0);   ADV(C1, S1, c2h1,  s2h1,  n2h1);
        FC0.z = h2b(C0); FS0.z = h2b(S0); FC1.z = h2b(C1); FS1.z = h2b(S1);
        ADV(C0, S0, c2h0,  s2h0,  n2h0);   ADV(C1, S1, c2h1,  s2h1,  n2h1);
        FC0.w = h2b(C0); FS0.w = h2b(S0); FC1.w = h2b(C1); FS1.w = h2b(S1);
        ADV(C0, S0, c10h0, s10h0, n10h0);  ADV(C1, S1, c10h1, s10h1, n10h1);
        // state now at the next pair's anchor (h += 16 total)

        const half8 fc0 = u4h(FC0), fc1 = u4h(FC1);
        acc[0][0] = __builtin_amdgcn_mfma_f32_32x32x16_f16(fc0, s8h(bc0), acc[0][0], 0, 0, 0);
        acc[0][1] = __builtin_amdgcn_mfma_f32_32x32x16_f16(fc0, s8h(bc1), acc[0][1], 0, 0, 0);
        acc[1][0] = __builtin_amdgcn_mfma_f32_32x32x16_f16(fc1, s8h(bc0), acc[1][0], 0, 0, 0);
        acc[1][1] = __builtin_amdgcn_mfma_f32_32x32x16_f16(fc1, s8h(bc1), acc[1][1], 0, 0, 0);

        const short8 bs0 = Wlds[((p*2 + 1)*2 + 0)*64 + lane];
        const short8 bs1 = Wlds[((p*2 + 1)*2 + 1)*64 + lane];
        const half8 fs0 = u4h(FS0), fs1 = u4h(FS1);
        acc[0][0] = __builtin_amdgcn_mfma_f32_32x32x16_f16(fs0, s8h(bs0), acc[0][0], 0, 0, 0);
        acc[0][1] = __builtin_amdgcn_mfma_f32_32x32x16_f16(fs0, s8h(bs1), acc[0][1], 0, 0, 0);
        acc[1][0] = __builtin_amdgcn_mfma_f32_32x32x16_f16(fs1, s8h(bs0), acc[1][0], 0, 0, 0);
        acc[1][1] = __builtin_amdgcn_mfma_f32_32x32x16_f16(fs1, s8h(bs1), acc[1][1], 0, 0, 0);
    }

    // Epilogue (verbatim R15, numerically verified). D: col=l&31, row=(q&3)+8*(q>>2)+4*kbd
    #pragma unroll
    for (int rt = 0; rt < 2; ++rt) {
        #pragma unroll
        for (int ct = 0; ct < 2; ++ct) {
            const float bv = ct ? bias1 : bias0;
            #pragma unroll
            for (int q = 0; q < 16; ++q) {
                const int row = base + rt*32 + (q & 3) + 8*(q >> 2) + 4*kbd;
                out[row*ODIM + ct*32 + col] = acc[rt][ct][q] + bv;
            }
        }
    }
}

extern "C" void kernel_launch(void* const* d_in, const int* in_sizes, int n_in,
                              void* d_out, int out_size, void* d_ws, size_t ws_size,
                              hipStream_t stream) {
    const float* x      = (const float*)d_in[0];
    const float* coeffs = (const float*)d_in[1];
    const float* bias   = (const float*)d_in[2];
    float* out = (float*)d_out;
    (void)in_sizes; (void)n_in; (void)out_size; (void)d_ws; (void)ws_size;
    hipLaunchKernelGGL(fourier_mfma, dim3(NBLOCKS), dim3(TPB), 0, stream, x, coeffs, bias, out);
}

// Round 19
// 38.891 us; speedup vs baseline: 1.2177x; 1.2177x over previous
//
#include <hip/hip_runtime.h>
#include <hip/hip_fp16.h>

typedef __attribute__((ext_vector_type(8))) short short8;
typedef __attribute__((ext_vector_type(8))) _Float16 half8;
typedef __attribute__((ext_vector_type(4))) float f32x4;
typedef __attribute__((ext_vector_type(2))) float f32x2;
typedef __attribute__((ext_vector_type(4))) unsigned int u32x4;

#define NROWS   262144
#define ODIM    64
#define NBLOCKS 256
#define TPB     1024          // 16 waves; 98 KB LDS -> 1 block/CU -> 4 waves/SIMD
#define INV2PI  0.15915494309189535f

__device__ __forceinline__ float cos2pi(float f){ float r; asm("v_cos_f32 %0, %1" : "=v"(r) : "v"(f)); return r; }
__device__ __forceinline__ float sin2pi(float f){ float r; asm("v_sin_f32 %0, %1" : "=v"(r) : "v"(f)); return r; }

__device__ __forceinline__ short f16_of(float f){
    union { _Float16 h; short s; } u; u.h = (_Float16)f; return u.s; }
__device__ __forceinline__ unsigned h2b(__half2 h){
    union { __half2 h; unsigned u; } x; x.h = h; return x.u; }
__device__ __forceinline__ half8 u4h(u32x4 v){ union{u32x4 u; half8 h;} x; x.u = v; return x.h; }
__device__ __forceinline__ half8 s8h(short8 v){ union{short8 s; half8 h;} x; x.s = v; return x.h; }

// one packed rotation: (C,S) <- (C*rc - S*rs, S*rc + C*rs), 2 features/inst
#define ADV(C, S, RC, RS, RN) do {                       \
    const __half2 _cn = __hfma2(C, RC, __hmul2(S, RN));  \
    const __half2 _sn = __hfma2(S, RC, __hmul2(C, RS));  \
    C = _cn; S = _sn;                                    \
} while (0)

// out[b,o] = sum_k F[b,k] W[o,k]; k = br*384 + i*128 + g; harmonic = g+1
// cos k-step kk (0..11) pairs with sin k-step kk+12 (identical harmonics).
// R19 = R17 with the iteration body re-scheduled: MFMAs grouped by A-fragment
// (acc reuse distance 4) and FEAT-B placed between A-cos and A-sin MFMA groups
// so chain-B VALU overlaps row-A MFMAs within the rolled iteration.
extern "C" __global__ void __launch_bounds__(TPB, 4)
__attribute__((amdgpu_waves_per_eu(4, 4)))
fourier_mfma(const float* __restrict__ x,
             const float* __restrict__ coeffs,
             const float* __restrict__ bias,
             float* __restrict__ out)
{
    // Fragment-ordered f16 weights: [ks][nt][lane] -> 8 f16 (one ds_read_b128)
    __shared__ short8 Wlds[24 * 4 * 64];   // 98304 B

    const int tid = threadIdx.x;

    // ---- one-time weight staging: fp32 global -> f16 fragments in LDS ----
    for (int fl = tid; fl < 24*4*64; fl += TPB) {
        const int ks = fl >> 8;
        const int nt = (fl >> 6) & 3;
        const int ln = fl & 63;
        const int o  = nt*16 + (ln & 15);   // B-frag: col = lane & 15
        const int kg = ln >> 4;             // k sub-band = 4*(lane>>4)
        union { short8 v; short s[8]; } fr;
        #pragma unroll
        for (int h = 0; h < 2; ++h) {
            const int kb  = ks*32 + h*16;
            const int br  = (kb >= 384) ? 1 : 0;
            const int rem = kb - br*384;
            const int ii  = rem >> 7;
            const int g0  = (rem & 127) + kg*4;
            const float* wp = coeffs + (((br*ODIM + o)*3 + ii) << 7) + g0;
            #pragma unroll
            for (int j = 0; j < 4; ++j) fr.s[h*4 + j] = f16_of(wp[j]);
        }
        Wlds[fl] = fr.v;
    }
    __syncthreads();

    const int lane = tid & 63;
    const int wid  = tid >> 6;
    const int mrow = lane & 15;     // A-frag row within 16-row tile
    const int kgrp = lane >> 4;     // k sub-band / D-row group
    const float hs = (float)(4*kgrp + 1);   // lane's anchor harmonic per i-block

    float bcol[4];
    #pragma unroll
    for (int nt = 0; nt < 4; ++nt) bcol[nt] = bias[nt*16 + mrow];

    const int unit = blockIdx.x * 16 + wid;   // 256*16 = 4096 units = NROWS/64
    const int base = unit * 64;

    // Two sequential 32-row passes; each pass handles a row-pair (rows r0, r1).
    #pragma unroll 1
    for (int rg = 0; rg < 2; ++rg) {
        const int rowA = base + (rg*2 + 0)*16 + mrow;
        const int rowB = base + (rg*2 + 1)*16 + mrow;

        f32x2 xr[3];
        #pragma unroll
        for (int i = 0; i < 3; ++i)
            xr[i] = (f32x2){ x[rowA*3 + i] * INV2PI, x[rowB*3 + i] * INV2PI };

        f32x4 acc[2][4];
        #pragma unroll
        for (int rr = 0; rr < 2; ++rr)
            #pragma unroll
            for (int nt = 0; nt < 4; ++nt)
                acc[rr][nt] = (f32x4){0.f, 0.f, 0.f, 0.f};

        // chain state + rotation constants (per row)
        __half2 C0, S0, C1, S1;
        __half2 c2h0, s2h0, n2h0, c14h0, s14h0, n14h0;
        __half2 c2h1, s2h1, n2h1, c14h1, s14h1, n14h1;

        #pragma unroll 1
        for (int kk = 0; kk < 12; ++kk) {          // cos k-step; sin is kk+12
            // early-issue this step's 8 b-frags (latency hides under feature gen)
            short8 bfr[8];                          // [branch*4 + nt], static idx
            #pragma unroll
            for (int nt = 0; nt < 4; ++nt) {
                bfr[nt]     = Wlds[(kk*4 + nt)*64 + lane];
                bfr[4 + nt] = Wlds[((kk + 12)*4 + nt)*64 + lane];
            }

            if ((kk & 3) == 0) {                    // re-anchor per i-block (uniform)
                const int i = kk >> 2;
                const f32x2 a = xr[i];
                {   // row 0
                    const float av = a.x;
                    float u0 = hs*av;        u0 -= floorf(u0);
                    float u1 = (hs+1.f)*av;  u1 -= floorf(u1);
                    C0 = __floats2half2_rn(cos2pi(u0), cos2pi(u1));
                    S0 = __floats2half2_rn(sin2pi(u0), sin2pi(u1));
                    float t2 = 2.f*av;       t2 -= floorf(t2);
                    const float c2 = cos2pi(t2), s2 = sin2pi(t2);
                    float t14 = 14.f*av;     t14 -= floorf(t14);
                    const float c14 = cos2pi(t14), s14 = sin2pi(t14);
                    c2h0  = __float2half2_rn(c2);   s2h0  = __float2half2_rn(s2);
                    n2h0  = __float2half2_rn(-s2);
                    c14h0 = __float2half2_rn(c14);  s14h0 = __float2half2_rn(s14);
                    n14h0 = __float2half2_rn(-s14);
                }
                {   // row 1
                    const float av = a.y;
                    float u0 = hs*av;        u0 -= floorf(u0);
                    float u1 = (hs+1.f)*av;  u1 -= floorf(u1);
                    C1 = __floats2half2_rn(cos2pi(u0), cos2pi(u1));
                    S1 = __floats2half2_rn(sin2pi(u0), sin2pi(u1));
                    float t2 = 2.f*av;       t2 -= floorf(t2);
                    const float c2 = cos2pi(t2), s2 = sin2pi(t2);
                    float t14 = 14.f*av;     t14 -= floorf(t14);
                    const float c14 = cos2pi(t14), s14 = sin2pi(t14);
                    c2h1  = __float2half2_rn(c2);   s2h1  = __float2half2_rn(s2);
                    n2h1  = __float2half2_rn(-s2);
                    c14h1 = __float2half2_rn(c14);  s14h1 = __float2half2_rn(s14);
                    n14h1 = __float2half2_rn(-s14);
                }
            }

            // ---- FEAT row A (chain 0) ----
            u32x4 FCA, FSA;
            FCA.x = h2b(C0); FSA.x = h2b(S0);
            ADV(C0, S0, c2h0,  s2h0,  n2h0);
            FCA.y = h2b(C0); FSA.y = h2b(S0);
            ADV(C0, S0, c14h0, s14h0, n14h0);
            FCA.z = h2b(C0); FSA.z = h2b(S0);
            ADV(C0, S0, c2h0,  s2h0,  n2h0);
            FCA.w = h2b(C0); FSA.w = h2b(S0);
            ADV(C0, S0, c14h0, s14h0, n14h0);
            const half8 fAc = u4h(FCA), fAs = u4h(FSA);

            // ---- A-cos MFMAs (overlap: nothing depends on chain 1 yet) ----
            #pragma unroll
            for (int nt = 0; nt < 4; ++nt)
                acc[0][nt] = __builtin_amdgcn_mfma_f32_16x16x32_f16(fAc, s8h(bfr[nt]), acc[0][nt], 0, 0, 0);

            // ---- FEAT row B (chain 1) — VALU overlaps A-cos MFMAs ----
            u32x4 FCB, FSB;
            FCB.x = h2b(C1); FSB.x = h2b(S1);
            ADV(C1, S1, c2h1,  s2h1,  n2h1);
            FCB.y = h2b(C1); FSB.y = h2b(S1);
            ADV(C1, S1, c14h1, s14h1, n14h1);
            FCB.z = h2b(C1); FSB.z = h2b(S1);
            ADV(C1, S1, c2h1,  s2h1,  n2h1);
            FCB.w = h2b(C1); FSB.w = h2b(S1);
            ADV(C1, S1, c14h1, s14h1, n14h1);
            const half8 fBc = u4h(FCB), fBs = u4h(FSB);

            // ---- A-sin, B-cos, B-sin MFMA groups (acc reuse distance 4) ----
            #pragma unroll
            for (int nt = 0; nt < 4; ++nt)
                acc[0][nt] = __builtin_amdgcn_mfma_f32_16x16x32_f16(fAs, s8h(bfr[4+nt]), acc[0][nt], 0, 0, 0);
            #pragma unroll
            for (int nt = 0; nt < 4; ++nt)
                acc[1][nt] = __builtin_amdgcn_mfma_f32_16x16x32_f16(fBc, s8h(bfr[nt]),   acc[1][nt], 0, 0, 0);
            #pragma unroll
            for (int nt = 0; nt < 4; ++nt)
                acc[1][nt] = __builtin_amdgcn_mfma_f32_16x16x32_f16(fBs, s8h(bfr[4+nt]), acc[1][nt], 0, 0, 0);
        }

        // Epilogue. D layout: col = lane&15, row = 4*(lane>>4) + reg  [m89-verified]
        #pragma unroll
        for (int rr = 0; rr < 2; ++rr) {
            const int row0 = base + (rg*2 + rr)*16 + kgrp*4;
            #pragma unroll
            for (int nt = 0; nt < 4; ++nt) {
                #pragma unroll
                for (int q = 0; q < 4; ++q) {
                    out[(row0 + q)*ODIM + nt*16 + mrow] = acc[rr][nt][q] + bcol[nt];
                }
            }
        }
    }
}

extern "C" void kernel_launch(void* const* d_in, const int* in_sizes, int n_in,
                              void* d_out, int out_size, void* d_ws, size_t ws_size,
                              hipStream_t stream) {
    const float* x      = (const float*)d_in[0];
    const float* coeffs = (const float*)d_in[1];
    const float* bias   = (const float*)d_in[2];
    float* out = (float*)d_out;
    (void)in_sizes; (void)n_in; (void)out_size; (void)d_ws; (void)ws_size;
    hipLaunchKernelGGL(fourier_mfma, dim3(NBLOCKS), dim3(TPB), 0, stream, x, coeffs, bias, out);
}